// Round 5
// baseline (569.563 us; speedup 1.0000x reference)
//
#include <hip/hip_runtime.h>
#include <hip/hip_bf16.h>
#include <math.h>

#define B_ 64
#define N_ 1024
#define E_ 16

typedef unsigned short ushort_t;
typedef __attribute__((ext_vector_type(8))) short bf16x8;
typedef __attribute__((ext_vector_type(4))) float f32x4;

__device__ __forceinline__ float sigmoidf_(float x) {
  return 1.0f / (1.0f + __expf(-x));
}
__device__ __forceinline__ ushort_t f2bf(float f) {  // RNE
  unsigned int u = __float_as_uint(f);
  u = (u + 0x7fffu + ((u >> 16) & 1u)) >> 16;
  return (ushort_t)u;
}
__device__ __forceinline__ float bf2f(ushort_t h) { return __uint_as_float((unsigned)h << 16); }
__device__ __forceinline__ void gload16(const void* g, void* l) {
  __builtin_amdgcn_global_load_lds(
      (const __attribute__((address_space(1))) unsigned int*)g,
      (__attribute__((address_space(3))) unsigned int*)l, 16, 0, 0);
}

// ---------- A = softmax(relu(emb@emb^T)) -> hi/lo bf16 [n][m] ----------
__global__ __launch_bounds__(256) void compute_A_kernel(const float* __restrict__ emb,
                                                        ushort_t* __restrict__ Ah,
                                                        ushort_t* __restrict__ Al) {
  __shared__ float embn[E_];
  __shared__ float red[256];
  const int n = blockIdx.x;
  const int t = threadIdx.x;
  if (t < E_) embn[t] = emb[n * E_ + t];
  __syncthreads();
  float s[4];
#pragma unroll
  for (int j = 0; j < 4; ++j) {
    const int m = j * 256 + t;
    const float* em = emb + m * E_;
    float acc = 0.f;
#pragma unroll
    for (int d = 0; d < E_; ++d) acc = fmaf(embn[d], em[d], acc);
    s[j] = fmaxf(acc, 0.f);
  }
  float mx = fmaxf(fmaxf(s[0], s[1]), fmaxf(s[2], s[3]));
  red[t] = mx;
  __syncthreads();
  for (int off = 128; off > 0; off >>= 1) {
    if (t < off) red[t] = fmaxf(red[t], red[t + off]);
    __syncthreads();
  }
  mx = red[0];
  __syncthreads();
  float e[4], lsum = 0.f;
#pragma unroll
  for (int j = 0; j < 4; ++j) { e[j] = __expf(s[j] - mx); lsum += e[j]; }
  red[t] = lsum;
  __syncthreads();
  for (int off = 128; off > 0; off >>= 1) {
    if (t < off) red[t] += red[t + off];
    __syncthreads();
  }
  const float inv = 1.0f / red[0];
#pragma unroll
  for (int j = 0; j < 4; ++j) {
    const float v = e[j] * inv;
    ushort_t h = f2bf(v);
    Ah[n * N_ + j * 256 + t] = h;
    Al[n * N_ + j * 256 + t] = f2bf(v - bf2f(h));
  }
}

// ---------- cat(xA,xB)[b][n][c] -> T0t hi/lo [(b*128+c)][n] ----------
__global__ __launch_bounds__(256) void build_T0t_kernel(const float* __restrict__ xA,
                                                        const float* __restrict__ xB,
                                                        ushort_t* __restrict__ Th,
                                                        ushort_t* __restrict__ Tl) {
  __shared__ float tile[128][129];  // [c][n-local]
  const int t = threadIdx.x;
  const int b = blockIdx.y;
  const int n0 = blockIdx.x << 7;
  const int c4 = (t & 31) << 2, nl = t >> 5;
#pragma unroll
  for (int p = 0; p < 16; ++p) {
    const int n = nl + (p << 3);
    const float4 v = (c4 < 64)
        ? *(const float4*)&xA[((size_t)b << 16) + ((size_t)(n0 + n) << 6) + c4]
        : *(const float4*)&xB[((size_t)b << 16) + ((size_t)(n0 + n) << 6) + c4 - 64];
    tile[c4 + 0][n] = v.x; tile[c4 + 1][n] = v.y;
    tile[c4 + 2][n] = v.z; tile[c4 + 3][n] = v.w;
  }
  __syncthreads();
  const int c = t >> 1, nc = (t & 1) << 6;
  const size_t obase = ((size_t)(b << 7) + c) * 1024 + n0 + nc;
#pragma unroll
  for (int u = 0; u < 64; u += 4) {
    ushort4 h, l;
    float v0 = tile[c][nc + u + 0], v1 = tile[c][nc + u + 1];
    float v2 = tile[c][nc + u + 2], v3 = tile[c][nc + u + 3];
    h.x = f2bf(v0); l.x = f2bf(v0 - bf2f(h.x));
    h.y = f2bf(v1); l.y = f2bf(v1 - bf2f(h.y));
    h.z = f2bf(v2); l.z = f2bf(v2 - bf2f(h.z));
    h.w = f2bf(v3); l.w = f2bf(v3 - bf2f(h.w));
    *(ushort4*)&Th[obase + u] = h;
    *(ushort4*)&Tl[obase + u] = l;
  }
}

// ---------- MFMA split-bf16 GEMM: D[n][j] = sum_m Aop[n][m] * Bop[j][m] ----------
// PHASE==1: v = acc ; write Yt hi/lo [j][n] AND Xp slot (hi/lo, [n][b][128])
// PHASE==0: v = 2*acc ; write Xp slot only (T0 term folded into W0' = W0-W2)
template <int PHASE>
__global__ __launch_bounds__(256, 2) void mfma_gemm_kernel(
    const ushort_t* __restrict__ Ah, const ushort_t* __restrict__ Al,   // [1024][1024]
    const ushort_t* __restrict__ Bh, const ushort_t* __restrict__ Bl,   // [8192][1024]
    ushort_t* __restrict__ Yth, ushort_t* __restrict__ Ytl,
    ushort_t* __restrict__ XpH, ushort_t* __restrict__ XpL) {  // pre-offset by slot*128
  __shared__ ushort_t smem[4 * 128 * 64];  // 64 KB
  ushort_t* Ah_s = smem;
  ushort_t* Al_s = smem + 8192;
  ushort_t* Bh_s = smem + 16384;
  ushort_t* Bl_s = smem + 24576;
  const int t = threadIdx.x;
  const int wave = t >> 6, lane = t & 63;
  const int n0 = blockIdx.y << 7;   // 8 tiles
  const int bcol = blockIdx.x;      // 64 j-tiles of 128 = one b each
  const int j0 = bcol << 7;
  const int wr = wave >> 1, wc = wave & 1;
  const int fr = lane & 15, fk = lane >> 4;

  f32x4 acc[4][4];
#pragma unroll
  for (int i = 0; i < 4; ++i)
#pragma unroll
    for (int j = 0; j < 4; ++j) acc[i][j] = (f32x4){0.f, 0.f, 0.f, 0.f};

  const int rsub = lane >> 3;
  const int cp = lane & 7;
  const int selem = (((cp << 4) ^ (rsub << 4)) >> 1);

  for (int k0 = 0; k0 < 1024; k0 += 64) {
    __syncthreads();
#pragma unroll
    for (int i = 0; i < 4; ++i) {
      const int q = (wave << 2) + i;
      const int row = (q << 3) + rsub;
      const int lo = (q << 9) + lane * 8;
      const size_t ga = (size_t)(n0 + row) * 1024 + k0 + selem;
      const size_t gb = (size_t)(j0 + row) * 1024 + k0 + selem;
      gload16(Ah + ga, Ah_s + lo);
      gload16(Al + ga, Al_s + lo);
      gload16(Bh + gb, Bh_s + lo);
      gload16(Bl + gb, Bl_s + lo);
    }
    __syncthreads();
#pragma unroll
    for (int ks = 0; ks < 2; ++ks) {
      bf16x8 ah[4], al[4], bh[4], bl[4];
#pragma unroll
      for (int mi = 0; mi < 4; ++mi) {
        const int r = (wr << 6) + (mi << 4) + fr;
        const int kb = ((ks << 6) + (fk << 4)) ^ ((r & 7) << 4);
        ah[mi] = *(const bf16x8*)((const char*)Ah_s + r * 128 + kb);
        al[mi] = *(const bf16x8*)((const char*)Al_s + r * 128 + kb);
      }
#pragma unroll
      for (int nj = 0; nj < 4; ++nj) {
        const int r = (wc << 6) + (nj << 4) + fr;
        const int kb = ((ks << 6) + (fk << 4)) ^ ((r & 7) << 4);
        bh[nj] = *(const bf16x8*)((const char*)Bh_s + r * 128 + kb);
        bl[nj] = *(const bf16x8*)((const char*)Bl_s + r * 128 + kb);
      }
#pragma unroll
      for (int mi = 0; mi < 4; ++mi)
#pragma unroll
        for (int nj = 0; nj < 4; ++nj) {
          acc[mi][nj] = __builtin_amdgcn_mfma_f32_16x16x32_bf16(ah[mi], bh[nj], acc[mi][nj], 0, 0, 0);
          acc[mi][nj] = __builtin_amdgcn_mfma_f32_16x16x32_bf16(ah[mi], bl[nj], acc[mi][nj], 0, 0, 0);
          acc[mi][nj] = __builtin_amdgcn_mfma_f32_16x16x32_bf16(al[mi], bh[nj], acc[mi][nj], 0, 0, 0);
        }
    }
  }

  __syncthreads();  // staging done; reuse smem as [128][128] hi/lo transpose tiles
  ushort_t* hiT = smem;            // 32 KB
  ushort_t* loT = smem + 16384;    // 32 KB
#pragma unroll
  for (int mi = 0; mi < 4; ++mi) {
    const int nl = (wr << 6) + (mi << 4) + (fk << 2);
#pragma unroll
    for (int nj = 0; nj < 4; ++nj) {
      const int jl = (wc << 6) + (nj << 4) + fr;
      const f32x4 vv = acc[mi][nj];
      ushort_t h[4], l[4];
#pragma unroll
      for (int r = 0; r < 4; ++r) {
        const float v = (PHASE == 1) ? vv[r] : 2.0f * vv[r];
        h[r] = f2bf(v);
        l[r] = f2bf(v - bf2f(h[r]));
      }
      if (PHASE == 1) {
        *(ushort4*)&Yth[(size_t)(j0 + jl) * 1024 + n0 + nl] = make_ushort4(h[0], h[1], h[2], h[3]);
        *(ushort4*)&Ytl[(size_t)(j0 + jl) * 1024 + n0 + nl] = make_ushort4(l[0], l[1], l[2], l[3]);
      }
#pragma unroll
      for (int r = 0; r < 4; ++r) {
        hiT[(nl + r) * 128 + jl] = h[r];
        loT[(nl + r) * 128 + jl] = l[r];
      }
    }
  }
  __syncthreads();
#pragma unroll
  for (int rr = 0; rr < 8; ++rr) {
    const int id = rr * 256 + t;     // 2048 16B-chunks
    const int nl = id >> 4, ch = id & 15;
    const size_t dstE = ((size_t)(n0 + nl) * 64 + bcol) * 256 + ch * 8;
    *(uint4*)&XpH[dstE] = *(const uint4*)((const char*)hiT + nl * 256 + ch * 16);
    *(uint4*)&XpL[dstE] = *(const uint4*)((const char*)loT + nl * 256 + ch * 16);
  }
}

// ---------- Wt hi/lo [n][64][384] bf16; k=0 slot holds (W0 - W2) combined ----------
template <int OW_SRC>  // 128 gate, 64 update
__global__ __launch_bounds__(256) void wcombine_t_kernel(const float* __restrict__ emb,
                                                         const float* __restrict__ Wp,
                                                         int o0,
                                                         ushort_t* __restrict__ WtH,
                                                         ushort_t* __restrict__ WtL) {
  __shared__ float es[8][E_];
  __shared__ ushort_t tileH[8][8][128];  // node, o-local, i  (16 KB)
  __shared__ ushort_t tileL[8][8][128];
  const int t = threadIdx.x;
  const int n0 = blockIdx.y * 8;
  const int k  = blockIdx.x >> 3;      // 0..2
  const int ob = blockIdx.x & 7;       // 0..7
  if (t < 8 * E_) es[t >> 4][t & 15] = emb[n0 * E_ + t];
  __syncthreads();
  const int i = t >> 1, oq = (t & 1) * 4;
  const size_t dstr = (size_t)384 * OW_SRC;
  const size_t src0 = (size_t)(k * 128 + i) * OW_SRC + o0 + ob * 8 + oq;
  const size_t src2 = (size_t)(2 * 128 + i) * OW_SRC + o0 + ob * 8 + oq;
  float4 acc[8] = {};
#pragma unroll 4
  for (int d = 0; d < E_; ++d) {
    float4 w = *(const float4*)&Wp[d * dstr + src0];
    if (k == 0) {
      const float4 w2 = *(const float4*)&Wp[d * dstr + src2];
      w.x -= w2.x; w.y -= w2.y; w.z -= w2.z; w.w -= w2.w;
    }
#pragma unroll
    for (int g = 0; g < 8; ++g) {
      const float e = es[g][d];
      acc[g].x = fmaf(e, w.x, acc[g].x);
      acc[g].y = fmaf(e, w.y, acc[g].y);
      acc[g].z = fmaf(e, w.z, acc[g].z);
      acc[g].w = fmaf(e, w.w, acc[g].w);
    }
  }
#pragma unroll
  for (int g = 0; g < 8; ++g) {
    ushort_t h;
    h = f2bf(acc[g].x); tileH[g][oq + 0][i] = h; tileL[g][oq + 0][i] = f2bf(acc[g].x - bf2f(h));
    h = f2bf(acc[g].y); tileH[g][oq + 1][i] = h; tileL[g][oq + 1][i] = f2bf(acc[g].y - bf2f(h));
    h = f2bf(acc[g].z); tileH[g][oq + 2][i] = h; tileL[g][oq + 2][i] = f2bf(acc[g].z - bf2f(h));
    h = f2bf(acc[g].w); tileH[g][oq + 3][i] = h; tileL[g][oq + 3][i] = f2bf(acc[g].w - bf2f(h));
  }
  __syncthreads();
  const int row = t >> 2, seg = t & 3;
  const int g = row >> 3, ol = row & 7;
  const size_t dst = ((size_t)(n0 + g) * 64 + ob * 8 + ol) * 384 + k * 128 + seg * 32;
  {
    const uint4* s = (const uint4*)&tileH[g][ol][seg * 32];
    uint4* dp = (uint4*)&WtH[dst];
    dp[0] = s[0]; dp[1] = s[1]; dp[2] = s[2]; dp[3] = s[3];
  }
  {
    const uint4* s = (const uint4*)&tileL[g][ol][seg * 32];
    uint4* dp = (uint4*)&WtL[dst];
    dp[0] = s[0]; dp[1] = s[1]; dp[2] = s[2]; dp[3] = s[3];
  }
}

// ---------- per-node MFMA contraction (O=64) + GRU epilogue ----------
// MODE 0: dst = sigmoid(a)                  (z -> d_out)
// MODE 1: dst = sigmoid(a) * state          (rs)
// MODE 2: dst = zb*state + (1-zb)*tanh(a)   (final out)
template <int MODE>
__global__ __launch_bounds__(256, 2) void pernode_mfma_kernel(
    const float* __restrict__ xA, const float* __restrict__ xB,   // [b][n][64]
    const ushort_t* __restrict__ XpH, const ushort_t* __restrict__ XpL,  // [n][64][256]
    const ushort_t* __restrict__ WtH, const ushort_t* __restrict__ WtL,  // [n][64][384]
    const float* __restrict__ emb, const float* __restrict__ bsrc, int bstride,
    const float* __restrict__ state, const float* __restrict__ zb,
    float* __restrict__ dst) {
  __shared__ ushort_t xh_s[64 * 128];  // 16 KB each
  __shared__ ushort_t xl_s[64 * 128];
  __shared__ ushort_t wh_s[64 * 128];
  __shared__ ushort_t wl_s[64 * 128];
  __shared__ float embn[E_];
  __shared__ float bias[64];
  const int n = blockIdx.x;
  const int t = threadIdx.x;
  if (t < E_) embn[t] = emb[n * E_ + t];
  __syncthreads();
  if (t < 64) {
    float a = 0.f;
#pragma unroll
    for (int d = 0; d < E_; ++d) a = fmaf(embn[d], bsrc[d * bstride + t], a);
    bias[t] = a;
  }
  const int wave = t >> 6, lane = t & 63;
  const int fr = lane & 15, fq = lane >> 4;
  f32x4 acc[4];
#pragma unroll
  for (int i = 0; i < 4; ++i) acc[i] = (f32x4){0.f, 0.f, 0.f, 0.f};

#pragma unroll
  for (int s = 0; s < 3; ++s) {
    __syncthreads();
    if (s == 0) {  // k0 = concat(xA, xB) f32 -> hi/lo bf16, swizzled ds_write
      const int b = t >> 2, q = t & 3;
      const float* srcp = (q < 2)
          ? xA + ((size_t)b << 16) + ((size_t)n << 6) + (q << 5)
          : xB + ((size_t)b << 16) + ((size_t)n << 6) + ((q - 2) << 5);
      float v[32];
#pragma unroll
      for (int j = 0; j < 8; ++j) *(float4*)&v[j * 4] = *(const float4*)&srcp[j * 4];
      const int swz = (b & 7) << 4;
#pragma unroll
      for (int jc = 0; jc < 4; ++jc) {
        unsigned int hh[4], ll[4];
#pragma unroll
        for (int e = 0; e < 4; ++e) {
          const float a0 = v[jc * 8 + 2 * e], a1 = v[jc * 8 + 2 * e + 1];
          const ushort_t h0 = f2bf(a0), h1 = f2bf(a1);
          const ushort_t l0 = f2bf(a0 - bf2f(h0)), l1 = f2bf(a1 - bf2f(h1));
          hh[e] = (unsigned)h0 | ((unsigned)h1 << 16);
          ll[e] = (unsigned)l0 | ((unsigned)l1 << 16);
        }
        const int dstb = b * 256 + (((q << 6) + (jc << 4)) ^ swz);
        *(uint4*)((char*)xh_s + dstb) = make_uint4(hh[0], hh[1], hh[2], hh[3]);
        *(uint4*)((char*)xl_s + dstb) = make_uint4(ll[0], ll[1], ll[2], ll[3]);
      }
    } else {  // Xp slots via global_load_lds, pre-swizzled source
#pragma unroll
      for (int r = 0; r < 4; ++r) {
        const int id = r * 256 + t;
        const int row = id >> 4, ch = id & 15;
        const int selem = (((ch << 4) ^ ((row & 7) << 4)) >> 1);
        const size_t so = ((size_t)n * 64 + row) * 256 + (s - 1) * 128 + selem;
        gload16(XpH + so, xh_s + id * 8);
        gload16(XpL + so, xl_s + id * 8);
      }
    }
#pragma unroll
    for (int r = 0; r < 4; ++r) {
      const int id = r * 256 + t;
      const int row = id >> 4, ch = id & 15;
      const int selem = (((ch << 4) ^ ((row & 7) << 4)) >> 1);
      const size_t so = ((size_t)n * 64 + row) * 384 + s * 128 + selem;
      gload16(WtH + so, wh_s + id * 8);
      gload16(WtL + so, wl_s + id * 8);
    }
    __syncthreads();
#pragma unroll
    for (int ks = 0; ks < 4; ++ks) {
      bf16x8 ah[4], al[4];
#pragma unroll
      for (int mi = 0; mi < 4; ++mi) {
        const int r = (mi << 4) + fr;
        const int kb = ((ks << 6) + (fq << 4)) ^ ((r & 7) << 4);
        ah[mi] = *(const bf16x8*)((const char*)xh_s + r * 256 + kb);
        al[mi] = *(const bf16x8*)((const char*)xl_s + r * 256 + kb);
      }
      const int rw = (wave << 4) + fr;
      const int kbw = ((ks << 6) + (fq << 4)) ^ ((rw & 7) << 4);
      const bf16x8 wh = *(const bf16x8*)((const char*)wh_s + rw * 256 + kbw);
      const bf16x8 wl = *(const bf16x8*)((const char*)wl_s + rw * 256 + kbw);
#pragma unroll
      for (int mi = 0; mi < 4; ++mi) {
        acc[mi] = __builtin_amdgcn_mfma_f32_16x16x32_bf16(ah[mi], wh, acc[mi], 0, 0, 0);
        acc[mi] = __builtin_amdgcn_mfma_f32_16x16x32_bf16(al[mi], wh, acc[mi], 0, 0, 0);
        acc[mi] = __builtin_amdgcn_mfma_f32_16x16x32_bf16(ah[mi], wl, acc[mi], 0, 0, 0);
      }
    }
  }

  const int o = (wave << 4) + fr;
  const float bia = bias[o];
#pragma unroll
  for (int mi = 0; mi < 4; ++mi) {
    const int b0 = (mi << 4) + (fq << 2);
    const f32x4 vv = acc[mi];
#pragma unroll
    for (int r = 0; r < 4; ++r) {
      const int b = b0 + r;
      const size_t base = ((size_t)b << 16) + ((size_t)n << 6);
      const float a = vv[r] + bia;
      if (MODE == 0) {
        dst[base + o] = sigmoidf_(a);
      } else if (MODE == 1) {
        dst[base + o] = sigmoidf_(a) * state[base + o];
      } else {
        const float z = zb[base + o], st = state[base + o];
        dst[base + o] = z * st + (1.f - z) * tanhf(a);
      }
    }
  }
}

extern "C" void kernel_launch(void* const* d_in, const int* in_sizes, int n_in,
                              void* d_out, int out_size, void* d_ws, size_t ws_size,
                              hipStream_t stream) {
  const float* x     = (const float*)d_in[0];
  const float* state = (const float*)d_in[1];
  const float* emb   = (const float*)d_in[2];
  const float* Wg    = (const float*)d_in[3];
  const float* bg    = (const float*)d_in[4];
  const float* Wu    = (const float*)d_in[5];
  const float* bu    = (const float*)d_in[6];
  float* out = (float*)d_out;

  char* w = (char*)d_ws;
  ushort_t* Ah   = (ushort_t*)(w);                             // 2 MB
  ushort_t* Al   = (ushort_t*)(w + ((size_t)2 << 20));         // 2
  ushort_t* T0th = (ushort_t*)(w + ((size_t)4 << 20));         // 16
  ushort_t* T0tl = (ushort_t*)(w + ((size_t)20 << 20));        // 16
  ushort_t* Y1th = (ushort_t*)(w + ((size_t)36 << 20));        // 16
  ushort_t* Y1tl = (ushort_t*)(w + ((size_t)52 << 20));        // 16
  ushort_t* XpH  = (ushort_t*)(w + ((size_t)68 << 20));        // 32  [n][64][256]
  ushort_t* XpL  = (ushort_t*)(w + ((size_t)100 << 20));       // 32
  ushort_t* WtH  = (ushort_t*)(w + ((size_t)132 << 20));       // 48  [n][64][384]
  ushort_t* WtL  = (ushort_t*)(w + ((size_t)180 << 20));       // 48
  float*    rs   = (float*)(w + ((size_t)228 << 20));          // 16 -> 244 MB
  float* zb = out;

  const dim3 gg(64, 8);
  const dim3 gt(8, 64);
  const dim3 gw(24, 128);

  compute_A_kernel<<<N_, 256, 0, stream>>>(emb, Ah, Al);
  wcombine_t_kernel<128><<<gw, 256, 0, stream>>>(emb, Wg, 0, WtH, WtL);

  // ---- gate pass ----
  build_T0t_kernel<<<gt, 256, 0, stream>>>(x, state, T0th, T0tl);
  mfma_gemm_kernel<1><<<gg, 256, 0, stream>>>(Ah, Al, T0th, T0tl, Y1th, Y1tl, XpH, XpL);
  mfma_gemm_kernel<0><<<gg, 256, 0, stream>>>(Ah, Al, Y1th, Y1tl, nullptr, nullptr,
                                              XpH + 128, XpL + 128);
  pernode_mfma_kernel<0><<<N_, 256, 0, stream>>>(x, state, XpH, XpL, WtH, WtL, emb, bg, 128,
                                                 state, nullptr, zb);
  wcombine_t_kernel<128><<<gw, 256, 0, stream>>>(emb, Wg, 64, WtH, WtL);
  pernode_mfma_kernel<1><<<N_, 256, 0, stream>>>(x, state, XpH, XpL, WtH, WtL, emb, bg + 64, 128,
                                                 state, nullptr, rs);

  // ---- update pass ----
  wcombine_t_kernel<64><<<gw, 256, 0, stream>>>(emb, Wu, 0, WtH, WtL);
  build_T0t_kernel<<<gt, 256, 0, stream>>>(x, rs, T0th, T0tl);
  mfma_gemm_kernel<1><<<gg, 256, 0, stream>>>(Ah, Al, T0th, T0tl, Y1th, Y1tl, XpH, XpL);
  mfma_gemm_kernel<0><<<gg, 256, 0, stream>>>(Ah, Al, Y1th, Y1tl, nullptr, nullptr,
                                              XpH + 128, XpL + 128);
  pernode_mfma_kernel<2><<<N_, 256, 0, stream>>>(x, rs, XpH, XpL, WtH, WtL, emb, bu, 64,
                                                 state, zb, out);
}